// Round 1
// baseline (421.546 us; speedup 1.0000x reference)
//
#include <hip/hip_runtime.h>
#include <math.h>

// WavelengthDependentPropagation: out = ifft2( fft2(x) * H(lam_c, fy, fx) )
// B=8, C=3, H=W=1024.  3-pass FFT pipeline + H-table precompute.
//   K0: build H table (3 x 1024 x 1024 complex, pre-scaled by 2^-20 = ifft2 norm)
//   K1: forward row FFT   (planes -> interleaved complex ws)
//   K2: per-8-column tile: fwd col FFT -> *H -> inv col FFT (in place in ws)
//   K3: inverse row FFT   (ws -> real plane, imag plane of d_out)

#define NIMG 24
static __device__ __forceinline__ void cmulf(float& ar, float& ai, float br, float bi) {
    float r = ar * br - ai * bi;
    float i = ar * bi + ai * br;
    ar = r; ai = i;
}

// ---------------- transfer function (mirrors the jnp fp32 chain exactly) ----
__device__ __forceinline__ float2 computeH(float lam, int ky, int kx) {
    int iy = (ky < 512) ? ky : ky - 1024;
    int ix = (kx < 512) ? kx : kx - 1024;
    // np.fft.fftfreq: f64 multiply by reciprocal, then .astype(float32)
    const double recip = 1.0 / (1024.0 * 8e-06);
    float fy = (float)((double)iy * recip);
    float fx = (float)((double)ix * recip);
    // fp32 chain, no FMA contraction (must match numpy's separate ops)
    float f2  = __fadd_rn(__fmul_rn(fy, fy), __fmul_rn(fx, fx));
    float l2  = __fmul_rn(lam, lam);
    float arg = __fsub_rn(1.0f, __fmul_rn(l2, f2));
    float2 h = make_float2(0.0f, 0.0f);
    if (arg > 0.0f) {
        float t  = __fdiv_rn(6.28318530717958647692f, lam); // f32(2*pi)/lam
        t        = __fmul_rn(t, 0.05f);                     // * z
        float kz = __fmul_rn(t, __fsqrt_rn(arg));           // * sqrt(arg), fp32
        // sin/cos of the exact fp32 kz, in double (correct range reduction;
        // kz ~ 7e5 rad, fp32-internal reduction would be garbage)
        double s, c;
        sincos((double)kz, &s, &c);
        const float sc = 9.5367431640625e-07f;              // 2^-20 (ifft2 norm)
        h = make_float2((float)c * sc, (float)s * sc);
    }
    return h;
}

__global__ __launch_bounds__(256) void build_H(float2* __restrict__ Htab,
                                               const float* __restrict__ wl) {
    int idx = blockIdx.x * 256 + threadIdx.x;    // 0 .. 3*1M
    int c   = idx >> 20;
    int rem = idx & 1048575;
    Htab[idx] = computeH(wl[c], rem >> 10, rem & 1023);
}

// ---------------- 1024-pt Stockham radix-4 FFT over contiguous LDS line -----
// 256 threads (j = 0..255), 4 complex each.  SIGN = -1 fwd, +1 inv (no 1/N).
template<int SIGN>
__device__ __forceinline__ void fft_line(float* re, float* im, int j) {
    #pragma unroll
    for (int s = 0; s < 5; ++s) {
        const int Ns = 1 << (2 * s);
        const int jm = j & (Ns - 1);
        float ang = (float)(SIGN * jm) * (3.14159265358979323846f / (2.0f * (float)Ns));
        float c1, s1; __sincosf(ang, &s1, &c1);
        float c2 = c1 * c1 - s1 * s1, s2 = 2.0f * c1 * s1;
        float c3 = c2 * c1 - s2 * s1, s3 = s2 * c1 + c2 * s1;
        float ar[4], ai[4];
        #pragma unroll
        for (int r = 0; r < 4; ++r) { ar[r] = re[j + (r << 8)]; ai[r] = im[j + (r << 8)]; }
        cmulf(ar[1], ai[1], c1, s1);
        cmulf(ar[2], ai[2], c2, s2);
        cmulf(ar[3], ai[3], c3, s3);
        float t0r = ar[0] + ar[2], t0i = ai[0] + ai[2];
        float t1r = ar[0] - ar[2], t1i = ai[0] - ai[2];
        float t2r = ar[1] + ar[3], t2i = ai[1] + ai[3];
        float t3r = ar[1] - ar[3], t3i = ai[1] - ai[3];
        float X0r = t0r + t2r, X0i = t0i + t2i;
        float X2r = t0r - t2r, X2i = t0i - t2i;
        float X1r = t1r - SIGN * t3i, X1i = t1i + SIGN * t3r;
        float X3r = t1r + SIGN * t3i, X3i = t1i - SIGN * t3r;
        __syncthreads();
        const int jd = ((j >> (2 * s)) << (2 * s + 2)) + jm;
        re[jd] = X0r;            im[jd] = X0i;
        re[jd + Ns] = X1r;       im[jd + Ns] = X1i;
        re[jd + 2 * Ns] = X2r;   im[jd + 2 * Ns] = X2i;
        re[jd + 3 * Ns] = X3r;   im[jd + 3 * Ns] = X3i;
        __syncthreads();
    }
}

// ---------------- K1: forward row FFT ---------------------------------------
__global__ __launch_bounds__(256) void fft_rows_fwd(const float* __restrict__ xr,
                                                    const float* __restrict__ xi,
                                                    float2* __restrict__ out) {
    __shared__ float re[1024], im[1024];
    const int j = threadIdx.x;
    const long long base = (long long)blockIdx.x * 1024;
    const float4* r4 = (const float4*)(xr + base);
    const float4* i4 = (const float4*)(xi + base);
    float4 a = r4[j], b = i4[j];
    re[4 * j + 0] = a.x; re[4 * j + 1] = a.y; re[4 * j + 2] = a.z; re[4 * j + 3] = a.w;
    im[4 * j + 0] = b.x; im[4 * j + 1] = b.y; im[4 * j + 2] = b.z; im[4 * j + 3] = b.w;
    __syncthreads();
    fft_line<-1>(re, im, j);
    float4* o4 = (float4*)(out + base);
    o4[2 * j + 0] = make_float4(re[4 * j + 0], im[4 * j + 0], re[4 * j + 1], im[4 * j + 1]);
    o4[2 * j + 1] = make_float4(re[4 * j + 2], im[4 * j + 2], re[4 * j + 3], im[4 * j + 3]);
}

// ---------------- K3: inverse row FFT + plane split --------------------------
__global__ __launch_bounds__(256) void ifft_rows_out(const float2* __restrict__ in,
                                                     float* __restrict__ outr,
                                                     float* __restrict__ outi) {
    __shared__ float re[1024], im[1024];
    const int j = threadIdx.x;
    const long long base = (long long)blockIdx.x * 1024;
    const float4* in4 = (const float4*)(in + base);
    float4 a = in4[2 * j + 0], b = in4[2 * j + 1];
    re[4 * j + 0] = a.x; im[4 * j + 0] = a.y;
    re[4 * j + 1] = a.z; im[4 * j + 1] = a.w;
    re[4 * j + 2] = b.x; im[4 * j + 2] = b.y;
    re[4 * j + 3] = b.z; im[4 * j + 3] = b.w;
    __syncthreads();
    fft_line<1>(re, im, j);
    float4* or4 = (float4*)(outr + base);
    float4* oi4 = (float4*)(outi + base);
    or4[j] = make_float4(re[4 * j + 0], re[4 * j + 1], re[4 * j + 2], re[4 * j + 3]);
    oi4[j] = make_float4(im[4 * j + 0], im[4 * j + 1], im[4 * j + 2], im[4 * j + 3]);
}

// ---------------- K2: column FFT * H * inverse column FFT --------------------
// 512 threads, 8 columns per block.  LDS: re[8*1024] + im[8*1024] floats (64KB).
// Column c stored rotated by 4c floats: physical = c*1024 + ((i + 4c) & 1023).
// Rotation makes both the tile-I/O lane pattern (c = t&7 fastest) and the FFT
// lane pattern (j fastest, c fixed) hit 2 words/bank = conflict-free floor.
template<int SIGN>
__device__ __forceinline__ void fft_4cols(float* RE, float* IM, int g, int j) {
    #pragma unroll
    for (int s = 0; s < 5; ++s) {
        const int Ns = 1 << (2 * s);
        const int jm = j & (Ns - 1);
        float ang = (float)(SIGN * jm) * (3.14159265358979323846f / (2.0f * (float)Ns));
        float c1, s1; __sincosf(ang, &s1, &c1);
        float c2 = c1 * c1 - s1 * s1, s2 = 2.0f * c1 * s1;
        float c3 = c2 * c1 - s2 * s1, s3 = s2 * c1 + c2 * s1;
        float xr[4][4], xi[4][4];
        #pragma unroll
        for (int cc = 0; cc < 4; ++cc) {
            const int c = (g << 2) + cc;
            const int cb = c << 10, rot = c << 2;
            #pragma unroll
            for (int r = 0; r < 4; ++r) {
                int p = cb + ((j + (r << 8) + rot) & 1023);
                xr[cc][r] = RE[p]; xi[cc][r] = IM[p];
            }
            cmulf(xr[cc][1], xi[cc][1], c1, s1);
            cmulf(xr[cc][2], xi[cc][2], c2, s2);
            cmulf(xr[cc][3], xi[cc][3], c3, s3);
            float t0r = xr[cc][0] + xr[cc][2], t0i = xi[cc][0] + xi[cc][2];
            float t1r = xr[cc][0] - xr[cc][2], t1i = xi[cc][0] - xi[cc][2];
            float t2r = xr[cc][1] + xr[cc][3], t2i = xi[cc][1] + xi[cc][3];
            float t3r = xr[cc][1] - xr[cc][3], t3i = xi[cc][1] - xi[cc][3];
            xr[cc][0] = t0r + t2r;            xi[cc][0] = t0i + t2i;
            xr[cc][2] = t0r - t2r;            xi[cc][2] = t0i - t2i;
            xr[cc][1] = t1r - SIGN * t3i;     xi[cc][1] = t1i + SIGN * t3r;
            xr[cc][3] = t1r + SIGN * t3i;     xi[cc][3] = t1i - SIGN * t3r;
        }
        __syncthreads();
        const int jd = ((j >> (2 * s)) << (2 * s + 2)) + jm;
        #pragma unroll
        for (int cc = 0; cc < 4; ++cc) {
            const int c = (g << 2) + cc;
            const int cb = c << 10, rot = c << 2;
            #pragma unroll
            for (int r = 0; r < 4; ++r) {
                int p = cb + ((jd + Ns * r + rot) & 1023);
                RE[p] = xr[cc][r]; IM[p] = xi[cc][r];
            }
        }
        __syncthreads();
    }
}

__global__ __launch_bounds__(512) void fft_cols_H(float2* __restrict__ ws,
                                                  const float2* __restrict__ Htab,
                                                  const float* __restrict__ wl) {
    extern __shared__ float lds[];
    float* RE = lds;
    float* IM = lds + 8192;
    const int t   = threadIdx.x;
    const int img = blockIdx.x >> 7;          // 0..23  (b*3 + c)
    const int x0  = (blockIdx.x & 127) << 3;  // column-group base
    const int lamIdx = img % 3;
    const long long ibase = (long long)img << 20;

    // --- load 1024x8 tile, rotated per-column -------------------------------
    {
        const int c = t & 7, yb = t >> 3;     // yb in [0,64)
        #pragma unroll
        for (int k = 0; k < 16; ++k) {
            int y = yb + (k << 6);
            float2 v = ws[ibase + (long long)y * 1024 + x0 + c];
            int p = (c << 10) + ((y + (c << 2)) & 1023);
            RE[p] = v.x; IM[p] = v.y;
        }
    }
    __syncthreads();

    const int g = t >> 8, j = t & 255;
    fft_4cols<-1>(RE, IM, g, j);              // ends with __syncthreads()

    // --- multiply by H(lam, ky, kx) * 2^-20 ---------------------------------
    {
        const int c = t & 7, yb = t >> 3;
        const int kx = x0 + c;
        const float lam = wl[lamIdx];
        #pragma unroll
        for (int k = 0; k < 16; ++k) {
            int ky = yb + (k << 6);
            float2 h = Htab ? Htab[((long long)lamIdx << 20) + (ky << 10) + kx]
                            : computeH(lam, ky, kx);
            int p = (c << 10) + ((ky + (c << 2)) & 1023);
            float ar = RE[p], ai = IM[p];
            RE[p] = ar * h.x - ai * h.y;
            IM[p] = ar * h.y + ai * h.x;
        }
    }
    __syncthreads();

    fft_4cols<1>(RE, IM, g, j);

    // --- store tile back (in place) -----------------------------------------
    {
        const int c = t & 7, yb = t >> 3;
        #pragma unroll
        for (int k = 0; k < 16; ++k) {
            int y = yb + (k << 6);
            int p = (c << 10) + ((y + (c << 2)) & 1023);
            ws[ibase + (long long)y * 1024 + x0 + c] = make_float2(RE[p], IM[p]);
        }
    }
}

// ---------------- launch ------------------------------------------------------
extern "C" void kernel_launch(void* const* d_in, const int* in_sizes, int n_in,
                              void* d_out, int out_size, void* d_ws, size_t ws_size,
                              hipStream_t stream) {
    const float* xr = (const float*)d_in[0];
    const float* xi = (const float*)d_in[1];
    const float* wl = (const float*)d_in[2];
    float* out = (float*)d_out;

    const size_t planeElems = (size_t)NIMG * 1024 * 1024;          // 24M
    float2* wsC = (float2*)d_ws;                                   // 192 MB
    const size_t needC = planeElems * sizeof(float2);
    const size_t needH = (size_t)3 * 1024 * 1024 * sizeof(float2); // 24 MB
    float2* Htab = nullptr;
    if (ws_size >= needC + needH) {
        Htab = (float2*)((char*)d_ws + needC);
        build_H<<<12288, 256, 0, stream>>>(Htab, wl);
    }
    fft_rows_fwd<<<NIMG * 1024, 256, 0, stream>>>(xr, xi, wsC);
    fft_cols_H<<<NIMG * 128, 512, 65536, stream>>>(wsC, Htab, wl);
    ifft_rows_out<<<NIMG * 1024, 256, 0, stream>>>(wsC, out, out + planeElems);
}

// Round 2
// 319.714 us; speedup vs baseline: 1.3185x; 1.3185x over previous
//
#include <hip/hip_runtime.h>
#include <math.h>

// WavelengthDependentPropagation: out = ifft2( fft2(x) * H(lam_c, fy, fx) )
// B=8, C=3, H=W=1024.  3-pass FFT pipeline + H-table precompute.
//   K0: build H table (3 x 1M complex, pre-scaled by 2^-20 = ifft2 norm)
//   K1: forward row FFT   (planes -> interleaved complex ws)
//   K2: per-8-column tile: fwd col FFT -> *H -> inv col FFT (in place in ws)
//       wave-private columns, fused-stage register FFT, XOR-swizzled LDS
//   K3: inverse row FFT   (ws -> real plane, imag plane of d_out)

#define NIMG 24

static __device__ __forceinline__ void cmulf(float& ar, float& ai, float br, float bi) {
    float r = ar * br - ai * bi;
    float i = ar * bi + ai * br;
    ar = r; ai = i;
}

__device__ __forceinline__ float2 cadd(float2 a, float2 b){ return make_float2(a.x+b.x, a.y+b.y); }
__device__ __forceinline__ float2 csub(float2 a, float2 b){ return make_float2(a.x-b.x, a.y-b.y); }
__device__ __forceinline__ float2 cmul(float2 a, float c, float s){ return make_float2(a.x*c - a.y*s, a.x*s + a.y*c); }

// ---------------- transfer function (mirrors the jnp fp32 chain exactly) ----
__device__ __forceinline__ float2 computeH(float lam, int ky, int kx) {
    int iy = (ky < 512) ? ky : ky - 1024;
    int ix = (kx < 512) ? kx : kx - 1024;
    const double recip = 1.0 / (1024.0 * 8e-06);
    float fy = (float)((double)iy * recip);
    float fx = (float)((double)ix * recip);
    float f2  = __fadd_rn(__fmul_rn(fy, fy), __fmul_rn(fx, fx));
    float l2  = __fmul_rn(lam, lam);
    float arg = __fsub_rn(1.0f, __fmul_rn(l2, f2));
    float2 h = make_float2(0.0f, 0.0f);
    if (arg > 0.0f) {
        float t  = __fdiv_rn(6.28318530717958647692f, lam);
        t        = __fmul_rn(t, 0.05f);
        float kz = __fmul_rn(t, __fsqrt_rn(arg));
        double s, c;
        sincos((double)kz, &s, &c);
        const float sc = 9.5367431640625e-07f;              // 2^-20
        h = make_float2((float)c * sc, (float)s * sc);
    }
    return h;
}

__global__ __launch_bounds__(256) void build_H(float2* __restrict__ Htab,
                                               const float* __restrict__ wl) {
    int idx = blockIdx.x * 256 + threadIdx.x;
    int c   = idx >> 20;
    int rem = idx & 1048575;
    Htab[idx] = computeH(wl[c], rem >> 10, rem & 1023);
}

// ---------------- radix-4 butterflies ---------------------------------------
template<int SIGN>
__device__ __forceinline__ void dft4nt(float2& a0, float2& a1, float2& a2, float2& a3) {
    float2 t0 = cadd(a0, a2), t1 = csub(a0, a2);
    float2 t2 = cadd(a1, a3), t3 = csub(a1, a3);
    a0 = cadd(t0, t2);
    a2 = csub(t0, t2);
    a1 = make_float2(t1.x - SIGN * t3.y, t1.y + SIGN * t3.x);
    a3 = make_float2(t1.x + SIGN * t3.y, t1.y - SIGN * t3.x);
}

template<int SIGN>
__device__ __forceinline__ void dft4(float2& a0, float2& a1, float2& a2, float2& a3,
                                     float c1, float s1) {
    float c2 = c1*c1 - s1*s1, s2 = 2.f*c1*s1;
    float c3 = c2*c1 - s2*s1, s3 = s2*c1 + c2*s1;
    a1 = cmul(a1, c1, s1);
    a2 = cmul(a2, c2, s2);
    a3 = cmul(a3, c3, s3);
    dft4nt<SIGN>(a0, a1, a2, a3);
}

// ---------------- 1024-pt Stockham radix-4 over contiguous LDS line (K1/K3) --
template<int SIGN>
__device__ __forceinline__ void fft_line(float* re, float* im, int j) {
    #pragma unroll
    for (int s = 0; s < 5; ++s) {
        const int Ns = 1 << (2 * s);
        const int jm = j & (Ns - 1);
        float ang = (float)(SIGN * jm) * (3.14159265358979323846f / (2.0f * (float)Ns));
        float c1, s1; __sincosf(ang, &s1, &c1);
        float c2 = c1 * c1 - s1 * s1, s2 = 2.0f * c1 * s1;
        float c3 = c2 * c1 - s2 * s1, s3 = s2 * c1 + c2 * s1;
        float ar[4], ai[4];
        #pragma unroll
        for (int r = 0; r < 4; ++r) { ar[r] = re[j + (r << 8)]; ai[r] = im[j + (r << 8)]; }
        cmulf(ar[1], ai[1], c1, s1);
        cmulf(ar[2], ai[2], c2, s2);
        cmulf(ar[3], ai[3], c3, s3);
        float t0r = ar[0] + ar[2], t0i = ai[0] + ai[2];
        float t1r = ar[0] - ar[2], t1i = ai[0] - ai[2];
        float t2r = ar[1] + ar[3], t2i = ai[1] + ai[3];
        float t3r = ar[1] - ar[3], t3i = ai[1] - ai[3];
        float X0r = t0r + t2r, X0i = t0i + t2i;
        float X2r = t0r - t2r, X2i = t0i - t2i;
        float X1r = t1r - SIGN * t3i, X1i = t1i + SIGN * t3r;
        float X3r = t1r + SIGN * t3i, X3i = t1i - SIGN * t3r;
        __syncthreads();
        const int jd = ((j >> (2 * s)) << (2 * s + 2)) + jm;
        re[jd] = X0r;            im[jd] = X0i;
        re[jd + Ns] = X1r;       im[jd + Ns] = X1i;
        re[jd + 2 * Ns] = X2r;   im[jd + 2 * Ns] = X2i;
        re[jd + 3 * Ns] = X3r;   im[jd + 3 * Ns] = X3i;
        __syncthreads();
    }
}

// ---------------- K1: forward row FFT ---------------------------------------
__global__ __launch_bounds__(256) void fft_rows_fwd(const float* __restrict__ xr,
                                                    const float* __restrict__ xi,
                                                    float2* __restrict__ out) {
    __shared__ float re[1024], im[1024];
    const int j = threadIdx.x;
    const long long base = (long long)blockIdx.x * 1024;
    const float4* r4 = (const float4*)(xr + base);
    const float4* i4 = (const float4*)(xi + base);
    float4 a = r4[j], b = i4[j];
    re[4 * j + 0] = a.x; re[4 * j + 1] = a.y; re[4 * j + 2] = a.z; re[4 * j + 3] = a.w;
    im[4 * j + 0] = b.x; im[4 * j + 1] = b.y; im[4 * j + 2] = b.z; im[4 * j + 3] = b.w;
    __syncthreads();
    fft_line<-1>(re, im, j);
    float4* o4 = (float4*)(out + base);
    o4[2 * j + 0] = make_float4(re[4 * j + 0], im[4 * j + 0], re[4 * j + 1], im[4 * j + 1]);
    o4[2 * j + 1] = make_float4(re[4 * j + 2], im[4 * j + 2], re[4 * j + 3], im[4 * j + 3]);
}

// ---------------- K3: inverse row FFT + plane split --------------------------
__global__ __launch_bounds__(256) void ifft_rows_out(const float2* __restrict__ in,
                                                     float* __restrict__ outr,
                                                     float* __restrict__ outi) {
    __shared__ float re[1024], im[1024];
    const int j = threadIdx.x;
    const long long base = (long long)blockIdx.x * 1024;
    const float4* in4 = (const float4*)(in + base);
    float4 a = in4[2 * j + 0], b = in4[2 * j + 1];
    re[4 * j + 0] = a.x; im[4 * j + 0] = a.y;
    re[4 * j + 1] = a.z; im[4 * j + 1] = a.w;
    re[4 * j + 2] = b.x; im[4 * j + 2] = b.y;
    re[4 * j + 3] = b.z; im[4 * j + 3] = b.w;
    __syncthreads();
    fft_line<1>(re, im, j);
    float4* or4 = (float4*)(outr + base);
    float4* oi4 = (float4*)(outi + base);
    or4[j] = make_float4(re[4 * j + 0], re[4 * j + 1], re[4 * j + 2], re[4 * j + 3]);
    oi4[j] = make_float4(im[4 * j + 0], im[4 * j + 1], im[4 * j + 2], im[4 * j + 3]);
}

// ---------------- K2: wave-private column FFTs ------------------------------
// Block: 512 threads = 8 waves; wave w owns column w of an 8-column tile.
// LDS: 8 columns x 1024 float2 = 64KB, column c at byte 8192*c.
// Swizzle (involution): phys = b ^ (((b>>7)&7)<<4)  -- applied to in-column
// byte address everywhere.  Makes all strided patterns conflict-free.
// Wave-local sync only inside the FFT; 4 __syncthreads() total in the kernel.

#define WSYNC() do { asm volatile("s_waitcnt lgkmcnt(0)" ::: "memory"); \
                     __builtin_amdgcn_wave_barrier(); } while (0)

// 1024-pt FFT: stages (0+1) in regs -> LDS -> (2+3) in regs -> LDS -> (4) in regs.
// Same Stockham index algebra as fft_line (verified): stage s reads {j+256r},
// writes {jd+Ns*q}, jd = (j>>2s)<<(2s+2) + (j&(Ns-1)).
template<int SIGN>
__device__ __forceinline__ void wave_fft(char* cb, int l) {
    const float SPI8   = SIGN * 0.39269908169872415481f;   // pi/8
    const float SPI32  = SIGN * 0.09817477042468103870f;   // pi/32
    const float SPI128 = SIGN * 0.02454369260617025967f;   // pi/128
    const float SPI512 = SIGN * 0.00613592315154256492f;   // pi/512
    // stride-64 access bases: pos = l + 64t, byte = 8l + 512t,
    // swizzle xor = (((l>>4) + 4*(t&1)) & 7) << 4  (separable: disjoint bits)
    const int swzE = (((l >> 4)    ) & 7) << 4;
    const int swzO = (((l >> 4) + 4) & 7) << 4;
    char* rbE = cb + ((8 * l) ^ swzE);
    char* rbO = cb + ((8 * l) ^ swzO);
    float2 v[4][4];

    // ---- Round A: stages 0 (j=l+64k) + 1 (j'=4l+q) -------------------------
    #pragma unroll
    for (int k = 0; k < 4; ++k) {
        #pragma unroll
        for (int r = 0; r < 4; ++r) {
            const int tt = k + 4 * r;
            v[k][r] = *(const float2*)(((tt & 1) ? rbO : rbE) + 512 * tt);
        }
    }
    #pragma unroll
    for (int k = 0; k < 4; ++k) dft4nt<SIGN>(v[k][0], v[k][1], v[k][2], v[k][3]);
    dft4nt<SIGN>(v[0][0], v[1][0], v[2][0], v[3][0]);          // q=0: twiddle=1
    #pragma unroll
    for (int q = 1; q < 4; ++q) {
        float s1, c1; __sincosf((float)q * SPI8, &s1, &c1);
        dft4<SIGN>(v[0][q], v[1][q], v[2][q], v[3][q], c1, s1);
    }
    // write pos 16l + 4p + q; byte = 128l + 16u, u = 2p + (q>>1); pairs contiguous
    {
        char* wb = cb + 128 * l;
        const int L7 = l & 7;
        #pragma unroll
        for (int p = 0; p < 4; ++p) {
            *(float4*)(wb + 16 * ((2*p+0) ^ L7)) =
                make_float4(v[p][0].x, v[p][0].y, v[p][1].x, v[p][1].y);
            *(float4*)(wb + 16 * ((2*p+1) ^ L7)) =
                make_float4(v[p][2].x, v[p][2].y, v[p][3].x, v[p][3].y);
        }
    }
    WSYNC();

    // ---- Round B: stages 2 (j=l+64k) + 3 (j'=64(l>>4)+(l&15)+16q) ----------
    #pragma unroll
    for (int k = 0; k < 4; ++k) {
        #pragma unroll
        for (int r = 0; r < 4; ++r) {
            const int tt = k + 4 * r;
            v[k][r] = *(const float2*)(((tt & 1) ? rbO : rbE) + 512 * tt);
        }
    }
    {
        const int jm2 = l & 15;
        float s1, c1; __sincosf((float)jm2 * SPI32, &s1, &c1);
        #pragma unroll
        for (int k = 0; k < 4; ++k) dft4<SIGN>(v[k][0], v[k][1], v[k][2], v[k][3], c1, s1);
        const int lo8 = 8 * (l & 15);                 // bits 3-6
        const int hi  = 2048 * (l >> 4);
        #pragma unroll
        for (int q = 0; q < 4; ++q) {
            float s1b, c1b; __sincosf((float)(jm2 + 16 * q) * SPI128, &s1b, &c1b);
            dft4<SIGN>(v[0][q], v[1][q], v[2][q], v[3][q], c1b, s1b);
            #pragma unroll
            for (int p = 0; p < 4; ++p) {
                const int K = ((q + 4 * p) & 7) << 4;  // swizzle const per (q,p)
                *(float2*)(cb + (lo8 ^ K) + hi + 128 * q + 512 * p) = v[p][q];
            }
        }
    }
    WSYNC();

    // ---- Round C: stage 4 (j''=l+64m), in-place on {l+64m+256q} ------------
    #pragma unroll
    for (int m = 0; m < 4; ++m) {
        #pragma unroll
        for (int r = 0; r < 4; ++r) {
            const int tt = m + 4 * r;
            v[m][r] = *(const float2*)(((tt & 1) ? rbO : rbE) + 512 * tt);
        }
    }
    #pragma unroll
    for (int m = 0; m < 4; ++m) {
        float s1, c1; __sincosf((float)(l + 64 * m) * SPI512, &s1, &c1);
        dft4<SIGN>(v[m][0], v[m][1], v[m][2], v[m][3], c1, s1);
        #pragma unroll
        for (int q = 0; q < 4; ++q) {
            const int tt = m + 4 * q;
            *(float2*)(((tt & 1) ? rbO : rbE) + 512 * tt) = v[m][q];
        }
    }
}

__global__ __launch_bounds__(512, 4) void fft_cols_H(float2* __restrict__ ws,
                                                     const float2* __restrict__ Htab,
                                                     const float* __restrict__ wl) {
    __shared__ float4 ldsb[4096];                     // 64 KB
    char* lds = (char*)ldsb;
    const int t   = threadIdx.x;
    const int img = blockIdx.x >> 7;                  // 0..23 (b*3 + c)
    const int x0  = (blockIdx.x & 127) << 3;          // column-group base
    const int lamIdx = img % 3;
    const long long ibase = (long long)img << 20;

    // I/O pattern: thread -> column-pair c2 = t&3 (cols 2c2, 2c2+1), row = t>>2
    const int c2  = t & 3;
    const int row = t >> 2;                           // 0..127
    const int xr  = (8 * row) ^ (((row >> 4) & 7) << 4);   // swizzled in-col byte
    char* io0 = lds + 16384 * c2 + xr;                // col 2c2
    char* io1 = io0 + 8192;                           // col 2c2+1

    // --- load 1024x8 tile (float4 = 2 complex, 2 adjacent columns) ----------
    {
        const float2* src = ws + ibase + x0 + 2 * c2;
        #pragma unroll
        for (int k = 0; k < 8; ++k) {
            int y = row + 128 * k;
            float4 g = *(const float4*)(src + (long long)y * 1024);
            *(float2*)(io0 + 1024 * k) = make_float2(g.x, g.y);
            *(float2*)(io1 + 1024 * k) = make_float2(g.z, g.w);
        }
    }
    __syncthreads();

    // --- forward column FFT: wave w owns column w ---------------------------
    const int w = t >> 6, l = t & 63;
    char* cb = lds + 8192 * w;
    wave_fft<-1>(cb, l);
    __syncthreads();

    // --- multiply by H(lam, ky, kx) * 2^-20 ---------------------------------
    {
        const float2* hsrc = Htab ? (Htab + (((long long)lamIdx) << 20) + x0 + 2 * c2)
                                  : nullptr;
        #pragma unroll
        for (int k = 0; k < 8; ++k) {
            int ky = row + 128 * k;
            float2 h0, h1;
            if (hsrc) {
                float4 hh = *(const float4*)(hsrc + (long long)ky * 1024);
                h0 = make_float2(hh.x, hh.y); h1 = make_float2(hh.z, hh.w);
            } else {
                h0 = computeH(wl[lamIdx], ky, x0 + 2 * c2);
                h1 = computeH(wl[lamIdx], ky, x0 + 2 * c2 + 1);
            }
            float2* p0 = (float2*)(io0 + 1024 * k);
            float2* p1 = (float2*)(io1 + 1024 * k);
            float2 a = *p0;
            *p0 = make_float2(a.x * h0.x - a.y * h0.y, a.x * h0.y + a.y * h0.x);
            float2 b = *p1;
            *p1 = make_float2(b.x * h1.x - b.y * h1.y, b.x * h1.y + b.y * h1.x);
        }
    }
    __syncthreads();

    // --- inverse column FFT -------------------------------------------------
    wave_fft<1>(cb, l);
    __syncthreads();

    // --- store tile back (in place) -----------------------------------------
    {
        float2* dst = ws + ibase + x0 + 2 * c2;
        #pragma unroll
        for (int k = 0; k < 8; ++k) {
            int y = row + 128 * k;
            float2 a = *(const float2*)(io0 + 1024 * k);
            float2 b = *(const float2*)(io1 + 1024 * k);
            *(float4*)(dst + (long long)y * 1024) = make_float4(a.x, a.y, b.x, b.y);
        }
    }
}

// ---------------- launch ------------------------------------------------------
extern "C" void kernel_launch(void* const* d_in, const int* in_sizes, int n_in,
                              void* d_out, int out_size, void* d_ws, size_t ws_size,
                              hipStream_t stream) {
    const float* xr = (const float*)d_in[0];
    const float* xi = (const float*)d_in[1];
    const float* wl = (const float*)d_in[2];
    float* out = (float*)d_out;

    const size_t planeElems = (size_t)NIMG * 1024 * 1024;          // 24M
    float2* wsC = (float2*)d_ws;                                   // 192 MB
    const size_t needC = planeElems * sizeof(float2);
    const size_t needH = (size_t)3 * 1024 * 1024 * sizeof(float2); // 24 MB
    float2* Htab = nullptr;
    if (ws_size >= needC + needH) {
        Htab = (float2*)((char*)d_ws + needC);
        build_H<<<12288, 256, 0, stream>>>(Htab, wl);
    }
    fft_rows_fwd<<<NIMG * 1024, 256, 0, stream>>>(xr, xi, wsC);
    fft_cols_H<<<NIMG * 128, 512, 0, stream>>>(wsC, Htab, wl);
    ifft_rows_out<<<NIMG * 1024, 256, 0, stream>>>(wsC, out, out + planeElems);
}